// Round 10
// baseline (158.349 us; speedup 1.0000x reference)
//
#include <hip/hip_runtime.h>
#include <hip/hip_bf16.h>
#include <math.h>

#define BB 4
#define LL 5
#define HSZ 32
#define WSZ 32
#define PP (HSZ*WSZ)   // 1024
#define CC 256
#define MM 8
#define DD 32
#define II 256
#define TT 2
#define NTOK (BB*PP*LL*II)   // 5,242,880
#define TILE_ELEMS 8192      // 32 pixels x 256 chans, bf16 ELEMENTS (16 KB)
#define SCALE 0.17677669529663687f  // 1/sqrt(32)

typedef short bf16x8 __attribute__((ext_vector_type(8)));
typedef float f32x4 __attribute__((ext_vector_type(4)));

static __device__ __forceinline__ ushort f2bf(float f) {
    unsigned u = __float_as_uint(f);
    unsigned r = (u + 0x7fffu + ((u >> 16) & 1u)) >> 16;   // RNE
    return (ushort)r;
}
static __device__ __forceinline__ float bf2f(ushort u) {
    return __uint_as_float(((unsigned)u) << 16);
}

// ---------------------------------------------------------------------------
// k_fold: merged weight-prep + LayerNorm/pack.  (R7-proven, unchanged.)
//  blk 0..63   : fold rel matrices into q/v projections (slots 0-7) + bEff
//  blk 64..191 : bf16 pack of Wk (slots 8,9) / Wa (slots 10,11)
//  blk 192..831: LayerNorm + A-frag pack of x -> xnPack (640 tiles)
// Pack layout per slot (65536 bf16): [nt(16)][kt(8)][lane(64)][j(8)],
//   B[k=kt*32+(lane>>4)*8+j][n=nt*16+(lane&15)]  (MFMA 16x16x32 B-frag).
// xnPack per tile (8192 bf16): [mt(2)][kt(8)][lane(64)][j(8)] A-frags.
// ---------------------------------------------------------------------------
__global__ __launch_bounds__(256) void k_fold(
    const float* __restrict__ Wq, const float* __restrict__ Wv,
    const float* __restrict__ Wk, const float* __restrict__ Wa,
    const float* __restrict__ bq, const float* __restrict__ bv,
    const float* __restrict__ rel_att, const float* __restrict__ rel_msg,
    const float* __restrict__ x,
    const float* __restrict__ lnw, const float* __restrict__ lnb,
    ushort* __restrict__ packW, float* __restrict__ bEff,
    ushort* __restrict__ xnPack)
{
    __shared__ float As[1024];
    __shared__ ushort Apack[8192];
    const int blk = blockIdx.x;
    const int tid = threadIdx.x;

    if (blk < 64) {
        const int p  = blk >> 5;
        const int t  = (blk >> 4) & 1;
        const int ts = (blk >> 3) & 1;
        const int m  = blk & 7;
        const float* A = (p == 0)
            ? rel_att + (size_t)((t * 2 + ts) * 8 + m) * 1024
            : rel_msg + (size_t)((ts * 2 + t) * 8 + m) * 1024;
        for (int i = tid; i < 1024; i += 256) As[i] = A[i];
        __syncthreads();

        const float* W = ((p == 0) ? Wq : Wv) + (size_t)t * 65536;
        const int k = tid;
        float wrow[32];
        #pragma unroll
        for (int u = 0; u < 8; ++u)
            *(float4*)&wrow[u * 4] = *(const float4*)&W[k * 256 + m * 32 + u * 4];

        const int slot = (p == 0 ? 0 : 4) + t * 2 + ts;
        ushort* base = packW + (size_t)slot * 65536;
        const int kt = k >> 5, j = k & 7, lq = ((k >> 3) & 3) * 16;
        #pragma unroll
        for (int q = 0; q < 32; ++q) {
            float acc = 0.f;
            #pragma unroll
            for (int pp = 0; pp < 32; ++pp) acc += wrow[pp] * As[pp * 32 + q];
            const int nt = m * 2 + (q >> 4);
            const int lane = lq + (q & 15);
            base[(size_t)((nt * 8 + kt) * 64 + lane) * 8 + j] = f2bf(acc);
        }
        if (tid < 32) {
            const int q = tid;
            const float* bi = ((p == 0) ? bq : bv) + t * 256 + m * 32;
            float acc = 0.f;
            #pragma unroll
            for (int pp = 0; pp < 32; ++pp) acc += bi[pp] * As[pp * 32 + q];
            bEff[(p ? 1024 : 0) + (t * 2 + ts) * 256 + m * 32 + q] = acc;
        }
    } else if (blk < 192) {
        const int idx = blk - 64;
        const int which = idx >> 6;              // 0 = Wk, 1 = Wa
        const int gi = (idx & 63) * 256 + tid;   // 0..16383
        const int t = gi >> 13;
        const int sub = gi & 8191;
        const float* src = ((which == 0) ? Wk : Wa) + (size_t)t * 65536;
        const int slot = (which == 0 ? 8 : 10) + t;
        const int nt = sub >> 9, kt = (sub >> 6) & 7, lane = sub & 63;
        const int k0 = kt * 32 + (lane >> 4) * 8;
        const int n  = nt * 16 + (lane & 15);
        ushort h[8];
        #pragma unroll
        for (int j = 0; j < 8; ++j) h[j] = f2bf(src[(size_t)(k0 + j) * 256 + n]);
        uint4 o;
        o.x = (unsigned)h[0] | ((unsigned)h[1] << 16);
        o.y = (unsigned)h[2] | ((unsigned)h[3] << 16);
        o.z = (unsigned)h[4] | ((unsigned)h[5] << 16);
        o.w = (unsigned)h[6] | ((unsigned)h[7] << 16);
        *(uint4*)(packW + (size_t)slot * 65536 + (size_t)sub * 8) = o;
    } else {
        const int lblk = blk - 192;
        const int bl  = lblk >> 5;
        const int pt  = lblk & 31;
        const int p0  = pt * 32;

        const int r  = tid >> 3;     // 0..31 pixel row
        const int jj = tid & 7;      // 8 threads/row, 32 chans each
        const float* xrow = x + ((size_t)bl * PP + p0 + r) * CC;
        float4 xv[8];
        float s1 = 0.f, s2 = 0.f;
        #pragma unroll
        for (int u = 0; u < 8; ++u) {
            xv[u] = *(const float4*)(xrow + jj * 32 + u * 4);
            s1 += xv[u].x + xv[u].y + xv[u].z + xv[u].w;
            s2 += xv[u].x * xv[u].x + xv[u].y * xv[u].y + xv[u].z * xv[u].z + xv[u].w * xv[u].w;
        }
        s1 += __shfl_xor(s1, 1); s1 += __shfl_xor(s1, 2); s1 += __shfl_xor(s1, 4);
        s2 += __shfl_xor(s2, 1); s2 += __shfl_xor(s2, 2); s2 += __shfl_xor(s2, 4);
        const float mu   = s1 * (1.0f / 256.0f);
        const float var  = s2 * (1.0f / 256.0f) - mu * mu;
        const float rstd = rsqrtf(var + 1e-5f);

        const int mt_r = r >> 4, rm = r & 15;
        #pragma unroll
        for (int u = 0; u < 8; ++u) {
            const int c0 = jj * 32 + u * 4;
            const float4 g  = *(const float4*)(lnw + c0);
            const float4 bt = *(const float4*)(lnb + c0);
            const ushort h0 = f2bf((xv[u].x - mu) * rstd * g.x + bt.x);
            const ushort h1 = f2bf((xv[u].y - mu) * rstd * g.y + bt.y);
            const ushort h2 = f2bf((xv[u].z - mu) * rstd * g.z + bt.z);
            const ushort h3 = f2bf((xv[u].w - mu) * rstd * g.w + bt.w);
            uint2 w2;
            w2.x = (unsigned)h0 | ((unsigned)h1 << 16);
            w2.y = (unsigned)h2 | ((unsigned)h3 << 16);
            const int kt   = c0 >> 5;
            const int lsub = rm + (((c0 >> 3) & 3) << 4);
            const int j0   = c0 & 7;
            *(uint2*)&Apack[(((mt_r * 8 + kt) * 64 + lsub) << 3) + j0] = w2;
        }
        __syncthreads();

        const size_t tbase = (size_t)lblk * TILE_ELEMS;
        #pragma unroll
        for (int u = 0; u < 4; ++u) {
            const int ch = (tid + u * 256) * 8;
            *(uint4*)&xnPack[tbase + ch] = *(const uint4*)&Apack[ch];
        }
    }
}

// ---------------------------------------------------------------------------
// k_proj: 5 per-type projections per block, A staged ONCE.
// 640 blocks = (bl, tile) x 512 thr (8 waves, full N=256 per mat).
// No barrier in the mat loop -> B-loads of mat m+1 overlap MFMA of mat m.
// xnPack read exactly once (10.5 MB total vs 52.5 MB in R9).
// Outputs in [b*5+l][pix][II] layout (row-contiguous stores).
// ---------------------------------------------------------------------------
__global__ __launch_bounds__(512) void k_proj(
    const ushort* __restrict__ xnPack, const float* __restrict__ prior,
    const ushort* __restrict__ packW, const float* __restrict__ bEff,
    const float* __restrict__ bk,
    ushort* __restrict__ qw0, ushort* __restrict__ qw1, ushort* __restrict__ kkO,
    ushort* __restrict__ vm0, ushort* __restrict__ vm1)
{
    __shared__ ushort As[8192];   // 16 KB, one A-tile in frag order

    const int tid  = threadIdx.x;
    const int blk  = blockIdx.x;     // 640 = bl(20) * 32 tiles
    const int bl   = blk >> 5;
    const int pt   = blk & 31;
    const int t    = (int)prior[(size_t)bl * (PP * 3) + 2];

    const int wv = tid >> 6, lane = tid & 63;

    // stage A-tile once
    const size_t tbase = (size_t)blk * TILE_ELEMS;
    #pragma unroll
    for (int u = 0; u < 2; ++u) {
        const int ch = (tid + u * 512) * 8;
        *(uint4*)&As[ch] = *(const uint4*)&xnPack[tbase + ch];
    }
    __syncthreads();

    const int cl = lane & 15, rq = lane >> 4;
    const int colA = wv * 32 + cl;
    const int colB = colA + 16;
    const int p0 = pt * 32;

    #pragma unroll 1
    for (int mat = 0; mat < 5; ++mat) {
        int slot; const float* bias;
        if (mat < 2)       { slot = t * 2 + mat;           bias = bEff + slot * 256; }
        else if (mat == 2) { slot = 8 + t;                 bias = bk + t * 256; }
        else               { slot = 4 + t * 2 + (mat - 3); bias = bEff + 1024 + (t * 2 + (mat - 3)) * 256; }
        ushort* dst = (mat == 0) ? qw0 : (mat == 1) ? qw1 : (mat == 2) ? kkO : (mat == 3) ? vm0 : vm1;
        const ushort* Bp = packW + (size_t)slot * 65536;

        // B-fragments for this mat: ntg = wv*2 + nn (full N across 8 waves)
        bf16x8 bfr[8][2];
        #pragma unroll
        for (int kt = 0; kt < 8; ++kt)
            #pragma unroll
            for (int nn = 0; nn < 2; ++nn) {
                const int ntg = wv * 2 + nn;
                bfr[kt][nn] = *(const bf16x8*)&Bp[(size_t)((ntg * 8 + kt) * 64 + lane) * 8];
            }

        f32x4 acc[2][2];
        #pragma unroll
        for (int mt = 0; mt < 2; ++mt)
            #pragma unroll
            for (int nn = 0; nn < 2; ++nn)
                acc[mt][nn] = (f32x4){0.f, 0.f, 0.f, 0.f};

        #pragma unroll
        for (int kt = 0; kt < 8; ++kt) {
            const bf16x8 a0 = *(const bf16x8*)&As[((0 * 8 + kt) * 64 + lane) << 3];
            const bf16x8 a1 = *(const bf16x8*)&As[((1 * 8 + kt) * 64 + lane) << 3];
            acc[0][0] = __builtin_amdgcn_mfma_f32_16x16x32_bf16(a0, bfr[kt][0], acc[0][0], 0, 0, 0);
            acc[0][1] = __builtin_amdgcn_mfma_f32_16x16x32_bf16(a0, bfr[kt][1], acc[0][1], 0, 0, 0);
            acc[1][0] = __builtin_amdgcn_mfma_f32_16x16x32_bf16(a1, bfr[kt][0], acc[1][0], 0, 0, 0);
            acc[1][1] = __builtin_amdgcn_mfma_f32_16x16x32_bf16(a1, bfr[kt][1], acc[1][1], 0, 0, 0);
        }

        const float biasA = bias[colA], biasB = bias[colB];
        #pragma unroll
        for (int mt = 0; mt < 2; ++mt) {
            const int row0 = p0 + mt * 16 + rq * 4;
            #pragma unroll
            for (int r2 = 0; r2 < 4; ++r2) {
                const size_t rb = ((size_t)bl * PP + row0 + r2) * II;
                dst[rb + colA] = f2bf(acc[mt][0][r2] + biasA);
                dst[rb + colB] = f2bf(acc[mt][1][r2] + biasB);
            }
        }
    }
}

// ---------------------------------------------------------------------------
// k_attn_lite: per-site (b,pixel) attention epilogue; inputs in
// [b*5+l][pix][II] layout; writes ao in A-frag pack order (aoPack).
// One wave per site.  (R7-proven version, unchanged.)
// ---------------------------------------------------------------------------
__global__ __launch_bounds__(256) void k_attn_lite(
    const ushort* __restrict__ qw0, const ushort* __restrict__ qw1,
    const ushort* __restrict__ kkI,
    const ushort* __restrict__ vm0, const ushort* __restrict__ vm1,
    const int* __restrict__ mask, const float* __restrict__ prior,
    ushort* __restrict__ aoPack)
{
    const int tid  = threadIdx.x;
    const int site = blockIdx.x * 4 + (tid >> 6);   // b*1024 + pix
    const int lane = tid & 63;
    const int b    = site >> 10;
    const int pix  = site & 1023;
    const int c0   = lane * 4;

    int ty[5];
    #pragma unroll
    for (int l = 0; l < 5; ++l)
        ty[l] = (int)prior[(size_t)(b * 5 + l) * (PP * 3) + 2];

    float qf[2][5][4], kf[5][4], vf[2][5][4];
    #pragma unroll
    for (int l = 0; l < 5; ++l) {
        const size_t base = (((size_t)(b * 5 + l) << 10) + pix) * II + c0;
        const ushort4 q0 = *(const ushort4*)(qw0 + base);
        const ushort4 q1 = *(const ushort4*)(qw1 + base);
        const ushort4 kv = *(const ushort4*)(kkI + base);
        const ushort4 v0 = *(const ushort4*)(vm0 + base);
        const ushort4 v1 = *(const ushort4*)(vm1 + base);
        qf[0][l][0] = bf2f(q0.x); qf[0][l][1] = bf2f(q0.y); qf[0][l][2] = bf2f(q0.z); qf[0][l][3] = bf2f(q0.w);
        qf[1][l][0] = bf2f(q1.x); qf[1][l][1] = bf2f(q1.y); qf[1][l][2] = bf2f(q1.z); qf[1][l][3] = bf2f(q1.w);
        kf[l][0]    = bf2f(kv.x); kf[l][1]    = bf2f(kv.y); kf[l][2]    = bf2f(kv.z); kf[l][3]    = bf2f(kv.w);
        vf[0][l][0] = bf2f(v0.x); vf[0][l][1] = bf2f(v0.y); vf[0][l][2] = bf2f(v0.z); vf[0][l][3] = bf2f(v0.w);
        vf[1][l][0] = bf2f(v1.x); vf[1][l][1] = bf2f(v1.y); vf[1][l][2] = bf2f(v1.z); vf[1][l][3] = bf2f(v1.w);
    }

    const int rr   = pix & 31;
    const int tile0 = b * 5 * 32 + (pix >> 5);    // + i*32
    const int mt   = rr >> 4;
    const int ktc  = c0 >> 5;
    const int lp   = (rr & 15) + 16 * ((c0 >> 3) & 3);
    const int j0   = c0 & 7;
    const int fofs = ((mt * 8 + ktc) * 64 + lp) * 8 + j0;

    #pragma unroll
    for (int i = 0; i < 5; ++i) {
        float lg[5];
        #pragma unroll
        for (int j = 0; j < 5; ++j) {
            const float s0 = qf[0][i][0] * kf[j][0] + qf[0][i][1] * kf[j][1]
                           + qf[0][i][2] * kf[j][2] + qf[0][i][3] * kf[j][3];
            const float s1 = qf[1][i][0] * kf[j][0] + qf[1][i][1] * kf[j][1]
                           + qf[1][i][2] * kf[j][2] + qf[1][i][3] * kf[j][3];
            float s = ty[j] ? s1 : s0;
            s += __shfl_xor(s, 1); s += __shfl_xor(s, 2); s += __shfl_xor(s, 4);
            const int mv = mask[((size_t)site * 5 + i) * 5 + j];
            lg[j] = mv ? s * SCALE : -1e9f;
        }
        float mx = lg[0];
        #pragma unroll
        for (int j = 1; j < 5; ++j) mx = fmaxf(mx, lg[j]);
        float ex[5], sum = 0.f;
        #pragma unroll
        for (int j = 0; j < 5; ++j) { ex[j] = __expf(lg[j] - mx); sum += ex[j]; }
        const float rs = 1.0f / sum;
        float o0 = 0.f, o1 = 0.f, o2 = 0.f, o3 = 0.f;
        #pragma unroll
        for (int j = 0; j < 5; ++j) {
            const float w = ex[j] * rs;
            o0 += w * (ty[i] ? vf[1][j][0] : vf[0][j][0]);
            o1 += w * (ty[i] ? vf[1][j][1] : vf[0][j][1]);
            o2 += w * (ty[i] ? vf[1][j][2] : vf[0][j][2]);
            o3 += w * (ty[i] ? vf[1][j][3] : vf[0][j][3]);
        }
        uint2 w2;
        w2.x = (unsigned)f2bf(o0) | ((unsigned)f2bf(o1) << 16);
        w2.y = (unsigned)f2bf(o2) | ((unsigned)f2bf(o3) << 16);
        *(uint2*)&aoPack[(size_t)(tile0 + i * 32) * TILE_ELEMS + fofs] = w2;
    }
}

// ---------------------------------------------------------------------------
// k_out: output projection (aoPack input) + final transpose, fp32 out.
// 640 blocks x 512 thr (1 tile, FULL N each): A-tile staged once; epilogue
// via padded fp32 LDS buffer -> float4 coalesced stores.  (R9 version.)
// ---------------------------------------------------------------------------
__global__ __launch_bounds__(512) void k_out(
    const ushort* __restrict__ aoPack, const float* __restrict__ prior,
    const ushort* __restrict__ packW, const float* __restrict__ ba,
    float* __restrict__ out)
{
    __shared__ ushort As[8192];         // 16 KB
    __shared__ float obufF[32 * 260];   // 33.3 KB (pad 4)

    const int tid  = threadIdx.x;
    const int blk  = blockIdx.x;
    const int bl   = blk >> 5;
    const int pt   = blk & 31;
    const int bbi  = bl / LL;
    const int l    = bl - bbi * LL;
    const int t    = (int)prior[(size_t)bl * (PP * 3) + 2];

    const int wv = tid >> 6, lane = tid & 63;
    const ushort* Bp = packW + (size_t)(10 + t) * 65536;
    bf16x8 bfr[8][2];
    #pragma unroll
    for (int kt = 0; kt < 8; ++kt)
        #pragma unroll
        for (int nn = 0; nn < 2; ++nn) {
            const int ntg = wv * 2 + nn;
            bfr[kt][nn] = *(const bf16x8*)&Bp[(size_t)((ntg * 8 + kt) * 64 + lane) * 8];
        }

    // stage A-tile
    const size_t tbase = (size_t)(bl * 32 + pt) * TILE_ELEMS;
    #pragma unroll
    for (int u = 0; u < 2; ++u) {
        const int ch = (tid + u * 512) * 8;
        *(uint4*)&As[ch] = *(const uint4*)&aoPack[tbase + ch];
    }
    __syncthreads();

    f32x4 acc[2][2];
    #pragma unroll
    for (int mt = 0; mt < 2; ++mt)
        #pragma unroll
        for (int nn = 0; nn < 2; ++nn)
            acc[mt][nn] = (f32x4){0.f, 0.f, 0.f, 0.f};

    #pragma unroll
    for (int kt = 0; kt < 8; ++kt) {
        const bf16x8 a0 = *(const bf16x8*)&As[((0 * 8 + kt) * 64 + lane) << 3];
        const bf16x8 a1 = *(const bf16x8*)&As[((1 * 8 + kt) * 64 + lane) << 3];
        acc[0][0] = __builtin_amdgcn_mfma_f32_16x16x32_bf16(a0, bfr[kt][0], acc[0][0], 0, 0, 0);
        acc[0][1] = __builtin_amdgcn_mfma_f32_16x16x32_bf16(a0, bfr[kt][1], acc[0][1], 0, 0, 0);
        acc[1][0] = __builtin_amdgcn_mfma_f32_16x16x32_bf16(a1, bfr[kt][0], acc[1][0], 0, 0, 0);
        acc[1][1] = __builtin_amdgcn_mfma_f32_16x16x32_bf16(a1, bfr[kt][1], acc[1][1], 0, 0, 0);
    }

    const int cl = lane & 15, rq = lane >> 4;
    const int colA = wv * 32 + cl;
    const int colB = colA + 16;
    const float biasA = ba[t * CC + colA];
    const float biasB = ba[t * CC + colB];
    #pragma unroll
    for (int mt = 0; mt < 2; ++mt) {
        const int rowb = mt * 16 + rq * 4;
        #pragma unroll
        for (int r2 = 0; r2 < 4; ++r2) {
            obufF[(rowb + r2) * 260 + colA] = acc[mt][0][r2] + biasA;
            obufF[(rowb + r2) * 260 + colB] = acc[mt][1][r2] + biasB;
        }
    }
    __syncthreads();

    // coalesced store: 64 lanes per row, 1 KB contiguous per row
    const int p0 = pt * 32;
    #pragma unroll
    for (int k2 = 0; k2 < 4; ++k2) {
        const int id  = tid + k2 * 512;
        const int row = id >> 6;            // 0..31
        const int ch  = (id & 63) * 4;      // float4 chunk within 256 cols
        const float4 v4 = *(const float4*)&obufF[row * 260 + ch];
        *(float4*)(out + ((size_t)(bbi * LL + l) * PP + p0 + row) * CC + ch) = v4;
    }
}

// ---------------------------------------------------------------------------
extern "C" void kernel_launch(void* const* d_in, const int* in_sizes, int n_in,
                              void* d_out, int out_size, void* d_ws, size_t ws_size,
                              hipStream_t stream) {
    const float* x       = (const float*)d_in[0];
    const int*   mask    = (const int*)d_in[1];
    const float* prior   = (const float*)d_in[2];
    const float* lnw     = (const float*)d_in[3];
    const float* lnb     = (const float*)d_in[4];
    const float* Wq      = (const float*)d_in[5];
    const float* bq      = (const float*)d_in[6];
    const float* Wk      = (const float*)d_in[7];
    const float* bk      = (const float*)d_in[8];
    const float* Wv      = (const float*)d_in[9];
    const float* bv      = (const float*)d_in[10];
    const float* Wa      = (const float*)d_in[11];
    const float* ba      = (const float*)d_in[12];
    const float* rel_att = (const float*)d_in[13];
    const float* rel_msg = (const float*)d_in[14];
    float* out = (float*)d_out;

    ushort* qw0    = (ushort*)d_ws;
    ushort* qw1    = qw0 + NTOK;
    ushort* kko    = qw1 + NTOK;
    ushort* vm0    = kko + NTOK;
    ushort* vm1    = vm0 + NTOK;
    ushort* aoPack = vm1 + NTOK;
    ushort* xnPack = aoPack + NTOK;
    ushort* packW  = xnPack + NTOK;                 // 12 * 65536 bf16
    float*  bEff   = (float*)(packW + 12 * 65536);  // 2048 fp32

    hipLaunchKernelGGL(k_fold, dim3(832), dim3(256), 0, stream,
                       Wq, Wv, Wk, Wa, bq, bv, rel_att, rel_msg,
                       x, lnw, lnb, packW, bEff, xnPack);
    hipLaunchKernelGGL(k_proj, dim3(640), dim3(512), 0, stream,
                       xnPack, prior, packW, bEff, bk, qw0, qw1, kko, vm0, vm1);
    hipLaunchKernelGGL(k_attn_lite, dim3(1024), dim3(256), 0, stream,
                       qw0, qw1, kko, vm0, vm1, mask, prior, aoPack);
    hipLaunchKernelGGL(k_out, dim3(640), dim3(512), 0, stream,
                       aoPack, prior, packW, ba, out);
}

// Round 11
// 149.341 us; speedup vs baseline: 1.0603x; 1.0603x over previous
//
#include <hip/hip_runtime.h>
#include <hip/hip_bf16.h>
#include <math.h>

#define BB 4
#define LL 5
#define HSZ 32
#define WSZ 32
#define PP (HSZ*WSZ)   // 1024
#define CC 256
#define MM 8
#define DD 32
#define II 256
#define TT 2
#define NTOK (BB*PP*LL*II)   // 5,242,880
#define TILE_ELEMS 8192      // 32 pixels x 256 chans, bf16 ELEMENTS (16 KB)
#define SCALE 0.17677669529663687f  // 1/sqrt(32)

typedef short bf16x8 __attribute__((ext_vector_type(8)));
typedef float f32x4 __attribute__((ext_vector_type(4)));

static __device__ __forceinline__ ushort f2bf(float f) {
    unsigned u = __float_as_uint(f);
    unsigned r = (u + 0x7fffu + ((u >> 16) & 1u)) >> 16;   // RNE
    return (ushort)r;
}
static __device__ __forceinline__ float bf2f(ushort u) {
    return __uint_as_float(((unsigned)u) << 16);
}

// ---------------------------------------------------------------------------
// k_fold: merged weight-prep + LayerNorm/pack.
//  blk 0..63   : fold rel matrices into q/v projections (slots 0-7) + bEff
//  blk 64..191 : bf16 pack of Wk (slots 8,9) / Wa (slots 10,11)
//  blk 192..831: LayerNorm + A-frag pack of x -> xnPack (640 tiles)
// Pack layout per slot (65536 bf16): [nt(16)][kt(8)][lane(64)][j(8)],
//   B[k=kt*32+(lane>>4)*8+j][n=nt*16+(lane&15)]  (MFMA 16x16x32 B-frag).
// xnPack per tile (8192 bf16): [mt(2)][kt(8)][lane(64)][j(8)] A-frags.
// ---------------------------------------------------------------------------
__global__ __launch_bounds__(256) void k_fold(
    const float* __restrict__ Wq, const float* __restrict__ Wv,
    const float* __restrict__ Wk, const float* __restrict__ Wa,
    const float* __restrict__ bq, const float* __restrict__ bv,
    const float* __restrict__ rel_att, const float* __restrict__ rel_msg,
    const float* __restrict__ x,
    const float* __restrict__ lnw, const float* __restrict__ lnb,
    ushort* __restrict__ packW, float* __restrict__ bEff,
    ushort* __restrict__ xnPack)
{
    __shared__ float As[1024];
    __shared__ ushort Apack[8192];
    const int blk = blockIdx.x;
    const int tid = threadIdx.x;

    if (blk < 64) {
        const int p  = blk >> 5;
        const int t  = (blk >> 4) & 1;
        const int ts = (blk >> 3) & 1;
        const int m  = blk & 7;
        const float* A = (p == 0)
            ? rel_att + (size_t)((t * 2 + ts) * 8 + m) * 1024
            : rel_msg + (size_t)((ts * 2 + t) * 8 + m) * 1024;
        for (int i = tid; i < 1024; i += 256) As[i] = A[i];
        __syncthreads();

        const float* W = ((p == 0) ? Wq : Wv) + (size_t)t * 65536;
        const int k = tid;
        float wrow[32];
        #pragma unroll
        for (int u = 0; u < 8; ++u)
            *(float4*)&wrow[u * 4] = *(const float4*)&W[k * 256 + m * 32 + u * 4];

        const int slot = (p == 0 ? 0 : 4) + t * 2 + ts;
        ushort* base = packW + (size_t)slot * 65536;
        const int kt = k >> 5, j = k & 7, lq = ((k >> 3) & 3) * 16;
        #pragma unroll
        for (int q = 0; q < 32; ++q) {
            float acc = 0.f;
            #pragma unroll
            for (int pp = 0; pp < 32; ++pp) acc += wrow[pp] * As[pp * 32 + q];
            const int nt = m * 2 + (q >> 4);
            const int lane = lq + (q & 15);
            base[(size_t)((nt * 8 + kt) * 64 + lane) * 8 + j] = f2bf(acc);
        }
        if (tid < 32) {
            const int q = tid;
            const float* bi = ((p == 0) ? bq : bv) + t * 256 + m * 32;
            float acc = 0.f;
            #pragma unroll
            for (int pp = 0; pp < 32; ++pp) acc += bi[pp] * As[pp * 32 + q];
            bEff[(p ? 1024 : 0) + (t * 2 + ts) * 256 + m * 32 + q] = acc;
        }
    } else if (blk < 192) {
        const int idx = blk - 64;
        const int which = idx >> 6;              // 0 = Wk, 1 = Wa
        const int gi = (idx & 63) * 256 + tid;   // 0..16383
        const int t = gi >> 13;
        const int sub = gi & 8191;
        const float* src = ((which == 0) ? Wk : Wa) + (size_t)t * 65536;
        const int slot = (which == 0 ? 8 : 10) + t;
        const int nt = sub >> 9, kt = (sub >> 6) & 7, lane = sub & 63;
        const int k0 = kt * 32 + (lane >> 4) * 8;
        const int n  = nt * 16 + (lane & 15);
        ushort h[8];
        #pragma unroll
        for (int j = 0; j < 8; ++j) h[j] = f2bf(src[(size_t)(k0 + j) * 256 + n]);
        uint4 o;
        o.x = (unsigned)h[0] | ((unsigned)h[1] << 16);
        o.y = (unsigned)h[2] | ((unsigned)h[3] << 16);
        o.z = (unsigned)h[4] | ((unsigned)h[5] << 16);
        o.w = (unsigned)h[6] | ((unsigned)h[7] << 16);
        *(uint4*)(packW + (size_t)slot * 65536 + (size_t)sub * 8) = o;
    } else {
        const int lblk = blk - 192;
        const int bl  = lblk >> 5;
        const int pt  = lblk & 31;
        const int p0  = pt * 32;

        const int r  = tid >> 3;     // 0..31 pixel row
        const int jj = tid & 7;      // 8 threads/row, 32 chans each
        const float* xrow = x + ((size_t)bl * PP + p0 + r) * CC;
        float4 xv[8];
        float s1 = 0.f, s2 = 0.f;
        #pragma unroll
        for (int u = 0; u < 8; ++u) {
            xv[u] = *(const float4*)(xrow + jj * 32 + u * 4);
            s1 += xv[u].x + xv[u].y + xv[u].z + xv[u].w;
            s2 += xv[u].x * xv[u].x + xv[u].y * xv[u].y + xv[u].z * xv[u].z + xv[u].w * xv[u].w;
        }
        s1 += __shfl_xor(s1, 1); s1 += __shfl_xor(s1, 2); s1 += __shfl_xor(s1, 4);
        s2 += __shfl_xor(s2, 1); s2 += __shfl_xor(s2, 2); s2 += __shfl_xor(s2, 4);
        const float mu   = s1 * (1.0f / 256.0f);
        const float var  = s2 * (1.0f / 256.0f) - mu * mu;
        const float rstd = rsqrtf(var + 1e-5f);

        const int mt_r = r >> 4, rm = r & 15;
        #pragma unroll
        for (int u = 0; u < 8; ++u) {
            const int c0 = jj * 32 + u * 4;
            const float4 g  = *(const float4*)(lnw + c0);
            const float4 bt = *(const float4*)(lnb + c0);
            const ushort h0 = f2bf((xv[u].x - mu) * rstd * g.x + bt.x);
            const ushort h1 = f2bf((xv[u].y - mu) * rstd * g.y + bt.y);
            const ushort h2 = f2bf((xv[u].z - mu) * rstd * g.z + bt.z);
            const ushort h3 = f2bf((xv[u].w - mu) * rstd * g.w + bt.w);
            uint2 w2;
            w2.x = (unsigned)h0 | ((unsigned)h1 << 16);
            w2.y = (unsigned)h2 | ((unsigned)h3 << 16);
            const int kt   = c0 >> 5;
            const int lsub = rm + (((c0 >> 3) & 3) << 4);
            const int j0   = c0 & 7;
            *(uint2*)&Apack[(((mt_r * 8 + kt) * 64 + lsub) << 3) + j0] = w2;
        }
        __syncthreads();

        const size_t tbase = (size_t)lblk * TILE_ELEMS;
        #pragma unroll
        for (int u = 0; u < 4; ++u) {
            const int ch = (tid + u * 256) * 8;
            *(uint4*)&xnPack[tbase + ch] = *(const uint4*)&Apack[ch];
        }
    }
}

// ---------------------------------------------------------------------------
// k_proj: 5 per-type projections, weight-stationary B in registers.
// Block = (mat, bl, pixel-group of 2 tiles, col-half). 3200 blocks, 256 thr.
// Outputs in [b*5+l][pix][II] layout (row-contiguous stores).
// Best-measured configuration (R7: 150.85 us).
// ---------------------------------------------------------------------------
__global__ __launch_bounds__(256) void k_proj(
    const ushort* __restrict__ xnPack, const float* __restrict__ prior,
    const ushort* __restrict__ packW, const float* __restrict__ bEff,
    const float* __restrict__ bk,
    ushort* __restrict__ qw0, ushort* __restrict__ qw1, ushort* __restrict__ kkO,
    ushort* __restrict__ vm0, ushort* __restrict__ vm1)
{
    __shared__ ushort As[8192];   // 16 KB, one A-tile in frag order

    const int tid  = threadIdx.x;
    const int blk  = blockIdx.x;
    const int mat  = blk / 640;
    const int rem  = blk - mat * 640;
    const int bl   = rem >> 5;
    const int sub  = rem & 31;
    const int pg   = sub >> 1;      // 16 groups of 2 tiles
    const int half = sub & 1;       // col half (128 cols)
    const int t    = (int)prior[(size_t)bl * (PP * 3) + 2];

    int slot; const float* bias;
    if (mat < 2)       { slot = t * 2 + mat;           bias = bEff + slot * 256; }
    else if (mat == 2) { slot = 8 + t;                 bias = bk + t * 256; }
    else               { slot = 4 + t * 2 + (mat - 3); bias = bEff + 1024 + (t * 2 + (mat - 3)) * 256; }
    ushort* dst = (mat == 0) ? qw0 : (mat == 1) ? qw1 : (mat == 2) ? kkO : (mat == 3) ? vm0 : vm1;

    const int wv = tid >> 6, lane = tid & 63;

    // B-fragments resident in registers: ntg = half*8 + wv*2 + nn
    const ushort* Bp = packW + (size_t)slot * 65536;
    bf16x8 bfr[8][2];
    #pragma unroll
    for (int kt = 0; kt < 8; ++kt)
        #pragma unroll
        for (int nn = 0; nn < 2; ++nn) {
            const int ntg = half * 8 + wv * 2 + nn;
            bfr[kt][nn] = *(const bf16x8*)&Bp[(size_t)((ntg * 8 + kt) * 64 + lane) * 8];
        }

    const int cl = lane & 15, rq = lane >> 4;
    const int colA = half * 128 + wv * 32 + cl;
    const int colB = colA + 16;
    const float biasA = bias[colA], biasB = bias[colB];

    #pragma unroll 1
    for (int tl = 0; tl < 2; ++tl) {
        const int pt = pg * 2 + tl;
        const size_t tbase = (size_t)(bl * 32 + pt) * TILE_ELEMS;
        __syncthreads();   // As reads of previous tile done
        #pragma unroll
        for (int u = 0; u < 4; ++u) {
            const int ch = (tid + u * 256) * 8;
            *(uint4*)&As[ch] = *(const uint4*)&xnPack[tbase + ch];
        }
        __syncthreads();

        f32x4 acc[2][2];
        #pragma unroll
        for (int mt = 0; mt < 2; ++mt)
            #pragma unroll
            for (int nn = 0; nn < 2; ++nn)
                acc[mt][nn] = (f32x4){0.f, 0.f, 0.f, 0.f};

        #pragma unroll
        for (int kt = 0; kt < 8; ++kt) {
            const bf16x8 a0 = *(const bf16x8*)&As[((0 * 8 + kt) * 64 + lane) << 3];
            const bf16x8 a1 = *(const bf16x8*)&As[((1 * 8 + kt) * 64 + lane) << 3];
            acc[0][0] = __builtin_amdgcn_mfma_f32_16x16x32_bf16(a0, bfr[kt][0], acc[0][0], 0, 0, 0);
            acc[0][1] = __builtin_amdgcn_mfma_f32_16x16x32_bf16(a0, bfr[kt][1], acc[0][1], 0, 0, 0);
            acc[1][0] = __builtin_amdgcn_mfma_f32_16x16x32_bf16(a1, bfr[kt][0], acc[1][0], 0, 0, 0);
            acc[1][1] = __builtin_amdgcn_mfma_f32_16x16x32_bf16(a1, bfr[kt][1], acc[1][1], 0, 0, 0);
        }

        const int p0 = pt * 32;
        #pragma unroll
        for (int mt = 0; mt < 2; ++mt) {
            const int row0 = p0 + mt * 16 + rq * 4;
            #pragma unroll
            for (int r2 = 0; r2 < 4; ++r2) {
                const size_t rb = ((size_t)bl * PP + row0 + r2) * II;
                dst[rb + colA] = f2bf(acc[mt][0][r2] + biasA);
                dst[rb + colB] = f2bf(acc[mt][1][r2] + biasB);
            }
        }
    }
}

// ---------------------------------------------------------------------------
// k_attn_lite: per-site (b,pixel) attention epilogue; inputs in
// [b*5+l][pix][II] layout; writes ao in A-frag pack order (aoPack).
// One wave per site.
// ---------------------------------------------------------------------------
__global__ __launch_bounds__(256) void k_attn_lite(
    const ushort* __restrict__ qw0, const ushort* __restrict__ qw1,
    const ushort* __restrict__ kkI,
    const ushort* __restrict__ vm0, const ushort* __restrict__ vm1,
    const int* __restrict__ mask, const float* __restrict__ prior,
    ushort* __restrict__ aoPack)
{
    const int tid  = threadIdx.x;
    const int site = blockIdx.x * 4 + (tid >> 6);   // b*1024 + pix
    const int lane = tid & 63;
    const int b    = site >> 10;
    const int pix  = site & 1023;
    const int c0   = lane * 4;

    int ty[5];
    #pragma unroll
    for (int l = 0; l < 5; ++l)
        ty[l] = (int)prior[(size_t)(b * 5 + l) * (PP * 3) + 2];

    float qf[2][5][4], kf[5][4], vf[2][5][4];
    #pragma unroll
    for (int l = 0; l < 5; ++l) {
        const size_t base = (((size_t)(b * 5 + l) << 10) + pix) * II + c0;
        const ushort4 q0 = *(const ushort4*)(qw0 + base);
        const ushort4 q1 = *(const ushort4*)(qw1 + base);
        const ushort4 kv = *(const ushort4*)(kkI + base);
        const ushort4 v0 = *(const ushort4*)(vm0 + base);
        const ushort4 v1 = *(const ushort4*)(vm1 + base);
        qf[0][l][0] = bf2f(q0.x); qf[0][l][1] = bf2f(q0.y); qf[0][l][2] = bf2f(q0.z); qf[0][l][3] = bf2f(q0.w);
        qf[1][l][0] = bf2f(q1.x); qf[1][l][1] = bf2f(q1.y); qf[1][l][2] = bf2f(q1.z); qf[1][l][3] = bf2f(q1.w);
        kf[l][0]    = bf2f(kv.x); kf[l][1]    = bf2f(kv.y); kf[l][2]    = bf2f(kv.z); kf[l][3]    = bf2f(kv.w);
        vf[0][l][0] = bf2f(v0.x); vf[0][l][1] = bf2f(v0.y); vf[0][l][2] = bf2f(v0.z); vf[0][l][3] = bf2f(v0.w);
        vf[1][l][0] = bf2f(v1.x); vf[1][l][1] = bf2f(v1.y); vf[1][l][2] = bf2f(v1.z); vf[1][l][3] = bf2f(v1.w);
    }

    const int rr   = pix & 31;
    const int tile0 = b * 5 * 32 + (pix >> 5);    // + i*32
    const int mt   = rr >> 4;
    const int ktc  = c0 >> 5;
    const int lp   = (rr & 15) + 16 * ((c0 >> 3) & 3);
    const int j0   = c0 & 7;
    const int fofs = ((mt * 8 + ktc) * 64 + lp) * 8 + j0;

    #pragma unroll
    for (int i = 0; i < 5; ++i) {
        float lg[5];
        #pragma unroll
        for (int j = 0; j < 5; ++j) {
            const float s0 = qf[0][i][0] * kf[j][0] + qf[0][i][1] * kf[j][1]
                           + qf[0][i][2] * kf[j][2] + qf[0][i][3] * kf[j][3];
            const float s1 = qf[1][i][0] * kf[j][0] + qf[1][i][1] * kf[j][1]
                           + qf[1][i][2] * kf[j][2] + qf[1][i][3] * kf[j][3];
            float s = ty[j] ? s1 : s0;
            s += __shfl_xor(s, 1); s += __shfl_xor(s, 2); s += __shfl_xor(s, 4);
            const int mv = mask[((size_t)site * 5 + i) * 5 + j];
            lg[j] = mv ? s * SCALE : -1e9f;
        }
        float mx = lg[0];
        #pragma unroll
        for (int j = 1; j < 5; ++j) mx = fmaxf(mx, lg[j]);
        float ex[5], sum = 0.f;
        #pragma unroll
        for (int j = 0; j < 5; ++j) { ex[j] = __expf(lg[j] - mx); sum += ex[j]; }
        const float rs = 1.0f / sum;
        float o0 = 0.f, o1 = 0.f, o2 = 0.f, o3 = 0.f;
        #pragma unroll
        for (int j = 0; j < 5; ++j) {
            const float w = ex[j] * rs;
            o0 += w * (ty[i] ? vf[1][j][0] : vf[0][j][0]);
            o1 += w * (ty[i] ? vf[1][j][1] : vf[0][j][1]);
            o2 += w * (ty[i] ? vf[1][j][2] : vf[0][j][2]);
            o3 += w * (ty[i] ? vf[1][j][3] : vf[0][j][3]);
        }
        uint2 w2;
        w2.x = (unsigned)f2bf(o0) | ((unsigned)f2bf(o1) << 16);
        w2.y = (unsigned)f2bf(o2) | ((unsigned)f2bf(o3) << 16);
        *(uint2*)&aoPack[(size_t)(tile0 + i * 32) * TILE_ELEMS + fofs] = w2;
    }
}

// ---------------------------------------------------------------------------
// k_out: output projection (aoPack input) + final transpose, fp32 out.
// 1280 blocks (1 tile, 1 col-half each); epilogue via padded fp32 LDS
// buffer -> float4 coalesced stores.  (R7 best-measured version.)
// ---------------------------------------------------------------------------
__global__ __launch_bounds__(256) void k_out(
    const ushort* __restrict__ aoPack, const float* __restrict__ prior,
    const ushort* __restrict__ packW, const float* __restrict__ ba,
    float* __restrict__ out)
{
    __shared__ ushort As[8192];     // 16 KB
    __shared__ float obufF[32 * 132];   // 16.9 KB, stride 132 -> conflict-free

    const int tid  = threadIdx.x;
    const int blk  = blockIdx.x;
    const int bl   = blk >> 6;
    const int sub  = blk & 63;
    const int pt   = sub >> 1;
    const int half = sub & 1;
    const int bbi  = bl / LL;
    const int l    = bl - bbi * LL;
    const int t    = (int)prior[(size_t)bl * (PP * 3) + 2];

    const int wv = tid >> 6, lane = tid & 63;
    const ushort* Bp = packW + (size_t)(10 + t) * 65536;
    bf16x8 bfr[8][2];
    #pragma unroll
    for (int kt = 0; kt < 8; ++kt)
        #pragma unroll
        for (int nn = 0; nn < 2; ++nn) {
            const int ntg = half * 8 + wv * 2 + nn;
            bfr[kt][nn] = *(const bf16x8*)&Bp[(size_t)((ntg * 8 + kt) * 64 + lane) * 8];
        }

    // stage A-tile
    const size_t tbase = (size_t)(bl * 32 + pt) * TILE_ELEMS;
    #pragma unroll
    for (int u = 0; u < 4; ++u) {
        const int ch = (tid + u * 256) * 8;
        *(uint4*)&As[ch] = *(const uint4*)&aoPack[tbase + ch];
    }
    __syncthreads();

    const int cl = lane & 15, rq = lane >> 4;
    const int colL_A = wv * 32 + cl;     // local col within the 128-half
    const int colL_B = colL_A + 16;
    const float biasA = ba[t * CC + half * 128 + colL_A];
    const float biasB = ba[t * CC + half * 128 + colL_B];

    f32x4 acc[2][2];
    #pragma unroll
    for (int mt = 0; mt < 2; ++mt)
        #pragma unroll
        for (int nn = 0; nn < 2; ++nn)
            acc[mt][nn] = (f32x4){0.f, 0.f, 0.f, 0.f};

    #pragma unroll
    for (int kt = 0; kt < 8; ++kt) {
        const bf16x8 a0 = *(const bf16x8*)&As[((0 * 8 + kt) * 64 + lane) << 3];
        const bf16x8 a1 = *(const bf16x8*)&As[((1 * 8 + kt) * 64 + lane) << 3];
        acc[0][0] = __builtin_amdgcn_mfma_f32_16x16x32_bf16(a0, bfr[kt][0], acc[0][0], 0, 0, 0);
        acc[0][1] = __builtin_amdgcn_mfma_f32_16x16x32_bf16(a0, bfr[kt][1], acc[0][1], 0, 0, 0);
        acc[1][0] = __builtin_amdgcn_mfma_f32_16x16x32_bf16(a1, bfr[kt][0], acc[1][0], 0, 0, 0);
        acc[1][1] = __builtin_amdgcn_mfma_f32_16x16x32_bf16(a1, bfr[kt][1], acc[1][1], 0, 0, 0);
    }

    #pragma unroll
    for (int mt = 0; mt < 2; ++mt) {
        const int rowb = mt * 16 + rq * 4;
        #pragma unroll
        for (int r2 = 0; r2 < 4; ++r2) {
            obufF[(rowb + r2) * 132 + colL_A] = acc[mt][0][r2] + biasA;
            obufF[(rowb + r2) * 132 + colL_B] = acc[mt][1][r2] + biasB;
        }
    }
    __syncthreads();

    // coalesced store: 32 lanes per row, 512 B contiguous per row-half
    const int p0 = pt * 32;
    #pragma unroll
    for (int k2 = 0; k2 < 4; ++k2) {
        const int id  = tid + k2 * 256;
        const int row = id >> 5;            // 0..31
        const int ch  = (id & 31) * 4;      // float4 chunk within 128 cols
        const float4 v4 = *(const float4*)&obufF[row * 132 + ch];
        *(float4*)(out + ((size_t)(bbi * LL + l) * PP + p0 + row) * CC + half * 128 + ch) = v4;
    }
}

// ---------------------------------------------------------------------------
extern "C" void kernel_launch(void* const* d_in, const int* in_sizes, int n_in,
                              void* d_out, int out_size, void* d_ws, size_t ws_size,
                              hipStream_t stream) {
    const float* x       = (const float*)d_in[0];
    const int*   mask    = (const int*)d_in[1];
    const float* prior   = (const float*)d_in[2];
    const float* lnw     = (const float*)d_in[3];
    const float* lnb     = (const float*)d_in[4];
    const float* Wq      = (const float*)d_in[5];
    const float* bq      = (const float*)d_in[6];
    const float* Wk      = (const float*)d_in[7];
    const float* bk      = (const float*)d_in[8];
    const float* Wv      = (const float*)d_in[9];
    const float* bv      = (const float*)d_in[10];
    const float* Wa      = (const float*)d_in[11];
    const float* ba      = (const float*)d_in[12];
    const float* rel_att = (const float*)d_in[13];
    const float* rel_msg = (const float*)d_in[14];
    float* out = (float*)d_out;

    ushort* qw0    = (ushort*)d_ws;
    ushort* qw1    = qw0 + NTOK;
    ushort* kko    = qw1 + NTOK;
    ushort* vm0    = kko + NTOK;
    ushort* vm1    = vm0 + NTOK;
    ushort* aoPack = vm1 + NTOK;
    ushort* xnPack = aoPack + NTOK;
    ushort* packW  = xnPack + NTOK;                 // 12 * 65536 bf16
    float*  bEff   = (float*)(packW + 12 * 65536);  // 2048 fp32

    hipLaunchKernelGGL(k_fold, dim3(832), dim3(256), 0, stream,
                       Wq, Wv, Wk, Wa, bq, bv, rel_att, rel_msg,
                       x, lnw, lnb, packW, bEff, xnPack);
    hipLaunchKernelGGL(k_proj, dim3(3200), dim3(256), 0, stream,
                       xnPack, prior, packW, bEff, bk, qw0, qw1, kko, vm0, vm1);
    hipLaunchKernelGGL(k_attn_lite, dim3(1024), dim3(256), 0, stream,
                       qw0, qw1, kko, vm0, vm1, mask, prior, aoPack);
    hipLaunchKernelGGL(k_out, dim3(1280), dim3(256), 0, stream,
                       aoPack, prior, packW, ba, out);
}